// Round 5
// baseline (265.074 us; speedup 1.0000x reference)
//
#include <hip/hip_runtime.h>
#include <math.h>

#define CLS_NUM 1000
#define FEAT 512

// ---------- helpers ----------

__device__ __forceinline__ bool detect_is64(const void* ys_raw) {
    // int64 (LE): high word of each element is 0, low word < 1000.
    // int32: odd words are random labels; all-zero across 16 slots ~ 1e-48.
    const int* y32 = (const int*)ys_raw;
    bool is64 = true;
#pragma unroll
    for (int k = 0; k < 16; ++k) {
        int lo = y32[2 * k], hi = y32[2 * k + 1];
        if (hi != 0 || (unsigned)lo >= (unsigned)CLS_NUM) is64 = false;
    }
    return is64;
}

__device__ __forceinline__ int load_label(const void* ys_raw, bool is64, int i) {
    return is64 ? (int)((const long long*)ys_raw)[i] : ((const int*)ys_raw)[i];
}

// One wave per sample: 512 floats = 64 lanes x 2 float4, fully coalesced.
__device__ __forceinline__ float wave_sqdist(const float* __restrict__ xs,
                                             const float* __restrict__ center,
                                             int i, int y, int lane) {
    const float4* xp = (const float4*)(xs + (size_t)i * FEAT);
    const float4* cp = (const float4*)(center + (size_t)y * FEAT);
    float4 x0 = xp[lane];
    float4 x1 = xp[lane + 64];
    float4 c0 = cp[lane];
    float4 c1 = cp[lane + 64];
    float d, s = 0.f;
    d = x0.x - c0.x; s += d * d;
    d = x0.y - c0.y; s += d * d;
    d = x0.z - c0.z; s += d * d;
    d = x0.w - c0.w; s += d * d;
    d = x1.x - c1.x; s += d * d;
    d = x1.y - c1.y; s += d * d;
    d = x1.z - c1.z; s += d * d;
    d = x1.w - c1.w; s += d * d;
#pragma unroll
    for (int off = 32; off; off >>= 1)
        s += __shfl_xor(s, off, 64);
    return s;
}

// ---------- fused dist + last-block finalize (node 2 of 2) ----------
// Requires distsum/count/arrival pre-zeroed (node 1 memset).

__global__ __launch_bounds__(256) void center_loss_fused(
    const float* __restrict__ xs,
    const void* __restrict__ ys_raw,
    const float* __restrict__ center,
    float* __restrict__ out,
    float* __restrict__ distsum,
    unsigned int* __restrict__ count,
    unsigned int* __restrict__ arrival,
    int n)
{
    const bool is64 = detect_is64(ys_raw);
    const int lane  = threadIdx.x & 63;
    const int wave  = (int)((blockIdx.x * blockDim.x + threadIdx.x) >> 6);
    const int nwave = (int)((gridDim.x * blockDim.x) >> 6);

    // Phase 1: fused per-class dist-sum + count (1000 bins, ~65 adds/bin).
    for (int i = wave; i < n; i += nwave) {
        const int y = load_label(ys_raw, is64, i);
        const float s = wave_sqdist(xs, center, i, y, lane);
        if (lane == 0) {
            atomicAdd(&distsum[y], sqrtf(s));
            atomicAdd(&count[y], 1u);
        }
    }

    // Phase 2: last block to arrive reduces sum_c distsum[c]/count[c].
    __shared__ unsigned int s_ticket;
    __threadfence();                      // release our atomics before ticket
    __syncthreads();
    if (threadIdx.x == 0)
        s_ticket = atomicAdd(arrival, 1u);
    __syncthreads();

    if (s_ticket == gridDim.x - 1) {
        __threadfence();                  // acquire: all blocks' atomics visible
        float s = 0.f;
        for (int c = (int)threadIdx.x; c < CLS_NUM; c += 256) {
            // Agent-scope atomic loads: bypass potentially-stale L1/L2 lines.
            unsigned cnt = __hip_atomic_load(&count[c], __ATOMIC_RELAXED,
                                             __HIP_MEMORY_SCOPE_AGENT);
            float ds = __hip_atomic_load(&distsum[c], __ATOMIC_RELAXED,
                                         __HIP_MEMORY_SCOPE_AGENT);
            if (cnt) s += ds / (float)cnt;
        }
#pragma unroll
        for (int off = 32; off; off >>= 1)
            s += __shfl_xor(s, off, 64);
        __shared__ float wsum[4];
        if ((threadIdx.x & 63) == 0) wsum[threadIdx.x >> 6] = s;
        __syncthreads();
        if (threadIdx.x == 0)
            out[0] = wsum[0] + wsum[1] + wsum[2] + wsum[3];
    }
}

extern "C" void kernel_launch(void* const* d_in, const int* in_sizes, int n_in,
                              void* d_out, int out_size, void* d_ws, size_t ws_size,
                              hipStream_t stream)
{
    const float* xs     = (const float*)d_in[0];
    const void*  ys     = d_in[1];
    const float* center = (const float*)d_in[2];
    float* out = (float*)d_out;

    // ws layout: [0,4000) distsum ; [4096,8096) count ; [8192] arrival
    float* distsum       = (float*)d_ws;
    unsigned int* count  = (unsigned int*)((char*)d_ws + 4096);
    unsigned int* arrival = (unsigned int*)((char*)d_ws + 8192);

    const int n = in_sizes[1];  // number of samples (ys element count)

    hipMemsetAsync(d_ws, 0, 12288, stream);
    center_loss_fused<<<2048, 256, 0, stream>>>(
        xs, ys, center, out, distsum, count, arrival, n);
}

// Round 6
// 60.200 us; speedup vs baseline: 4.4032x; 4.4032x over previous
//
#include <hip/hip_runtime.h>
#include <math.h>

#define CLS_NUM 1000
#define FEAT 512
#define NPART 4            // count partial tables (one per count block)
#define CB_THREADS 1024
#define CB_WAVES (CB_THREADS / 64)

// ---------- helpers ----------

__device__ __forceinline__ bool detect_is64(const void* ys_raw) {
    // int64 (LE): high word of each element is 0, low word < 1000.
    // int32: odd words are random labels; all-zero across 16 slots ~ 1e-48.
    const int* y32 = (const int*)ys_raw;
    bool is64 = true;
#pragma unroll
    for (int k = 0; k < 16; ++k) {
        int lo = y32[2 * k], hi = y32[2 * k + 1];
        if (hi != 0 || (unsigned)lo >= (unsigned)CLS_NUM) is64 = false;
    }
    return is64;
}

__device__ __forceinline__ int load_label(const void* ys_raw, bool is64, int i) {
    return is64 ? (int)((const long long*)ys_raw)[i] : ((const int*)ys_raw)[i];
}

// ---------- node 1: label histogram into NPART partial tables ----------
// No global pre-zero needed: LDS sub-hists are zeroed in-kernel and the
// partial tables are fully STORED (not accumulated). Also zeroes out[0]
// (stream-ordered before dist_kernel's atomics).

__global__ __launch_bounds__(CB_THREADS) void count_hist(
    const void* __restrict__ ys_raw,
    unsigned* __restrict__ countP,   // [NPART][CLS_NUM]
    float* __restrict__ out,
    int n)
{
    __shared__ unsigned hist[CB_WAVES][CLS_NUM];
    const int t = (int)threadIdx.x;
    const bool is64 = detect_is64(ys_raw);

    for (int idx = t; idx < CB_WAVES * CLS_NUM; idx += CB_THREADS)
        ((unsigned*)hist)[idx] = 0u;
    __syncthreads();

    const int per_blk = (n + NPART - 1) / NPART;
    const int base = (int)blockIdx.x * per_blk;
    const int end  = min(base + per_blk, n);
    const int w = t >> 6;
    for (int i = base + t; i < end; i += CB_THREADS)
        atomicAdd(&hist[w][load_label(ys_raw, is64, i)], 1u);
    __syncthreads();

    for (int c = t; c < CLS_NUM; c += CB_THREADS) {
        unsigned s = 0;
#pragma unroll
        for (int k = 0; k < CB_WAVES; ++k) s += hist[k][c];
        countP[blockIdx.x * CLS_NUM + c] = s;
    }
    if (blockIdx.x == 0 && t == 0) out[0] = 0.f;
}

// ---------- node 2: streaming dist pass, fused divide, block-reduced ----------
// One wave per sample (512 floats = 64 lanes x 2 float4, fully coalesced),
// two independent sample streams per iteration to hide the shuffle chain.

__global__ __launch_bounds__(256) void dist_kernel(
    const float* __restrict__ xs,
    const void* __restrict__ ys_raw,
    const float* __restrict__ center,
    const unsigned* __restrict__ countP,
    float* __restrict__ out,
    int n)
{
    const bool is64 = detect_is64(ys_raw);
    const int lane  = (int)threadIdx.x & 63;
    const int wave  = (int)((blockIdx.x * blockDim.x + threadIdx.x) >> 6);
    const int nwave = (int)((gridDim.x * blockDim.x) >> 6);

    __shared__ float bsum;
    if (threadIdx.x == 0) bsum = 0.f;
    __syncthreads();

    float wsum = 0.f;  // meaningful on lane 0 only

    for (int i = wave; i < n; i += 2 * nwave) {
        const int i2 = i + nwave;
        const bool has2 = (i2 < n);

        // ---- issue all loads for both streams up front ----
        const int y1 = load_label(ys_raw, is64, i);
        const float4* xp1 = (const float4*)(xs + (size_t)i * FEAT);
        const float4* cp1 = (const float4*)(center + (size_t)y1 * FEAT);
        float4 a0 = xp1[lane], a1 = xp1[lane + 64];
        float4 b0 = cp1[lane], b1 = cp1[lane + 64];

        float4 c0, c1, d0, d1;
        int y2 = 0;
        if (has2) {
            y2 = load_label(ys_raw, is64, i2);
            const float4* xp2 = (const float4*)(xs + (size_t)i2 * FEAT);
            const float4* cp2 = (const float4*)(center + (size_t)y2 * FEAT);
            c0 = xp2[lane]; c1 = xp2[lane + 64];
            d0 = cp2[lane]; d1 = cp2[lane + 64];
        }

        // ---- FMA chains ----
        float e, s1 = 0.f;
        e = a0.x - b0.x; s1 += e * e;
        e = a0.y - b0.y; s1 += e * e;
        e = a0.z - b0.z; s1 += e * e;
        e = a0.w - b0.w; s1 += e * e;
        e = a1.x - b1.x; s1 += e * e;
        e = a1.y - b1.y; s1 += e * e;
        e = a1.z - b1.z; s1 += e * e;
        e = a1.w - b1.w; s1 += e * e;

        float s2 = 0.f;
        if (has2) {
            e = c0.x - d0.x; s2 += e * e;
            e = c0.y - d0.y; s2 += e * e;
            e = c0.z - d0.z; s2 += e * e;
            e = c0.w - d0.w; s2 += e * e;
            e = c1.x - d1.x; s2 += e * e;
            e = c1.y - d1.y; s2 += e * e;
            e = c1.z - d1.z; s2 += e * e;
            e = c1.w - d1.w; s2 += e * e;
        }

        // ---- interleaved wave reductions (two independent chains) ----
#pragma unroll
        for (int off = 32; off; off >>= 1) {
            s1 += __shfl_xor(s1, off, 64);
            s2 += __shfl_xor(s2, off, 64);
        }

        if (lane == 0) {
            unsigned cnt1 = countP[y1] + countP[CLS_NUM + y1] +
                            countP[2 * CLS_NUM + y1] + countP[3 * CLS_NUM + y1];
            wsum += sqrtf(s1) / (float)cnt1;
            if (has2) {
                unsigned cnt2 = countP[y2] + countP[CLS_NUM + y2] +
                                countP[2 * CLS_NUM + y2] + countP[3 * CLS_NUM + y2];
                wsum += sqrtf(s2) / (float)cnt2;
            }
        }
    }

    if (lane == 0) atomicAdd(&bsum, wsum);   // LDS atomic, one per wave
    __syncthreads();
    if (threadIdx.x == 0) atomicAdd(out, bsum);  // one global atomic per block
}

extern "C" void kernel_launch(void* const* d_in, const int* in_sizes, int n_in,
                              void* d_out, int out_size, void* d_ws, size_t ws_size,
                              hipStream_t stream)
{
    const float* xs     = (const float*)d_in[0];
    const void*  ys     = d_in[1];
    const float* center = (const float*)d_in[2];
    float* out = (float*)d_out;

    unsigned* countP = (unsigned*)d_ws;  // [NPART][CLS_NUM], fully stored each call

    const int n = in_sizes[1];  // number of samples (ys element count)

    count_hist<<<NPART, CB_THREADS, 0, stream>>>(ys, countP, out, n);
    dist_kernel<<<2048, 256, 0, stream>>>(xs, ys, center, countP, out, n);
}

// Round 7
// 59.745 us; speedup vs baseline: 4.4368x; 1.0076x over previous
//
#include <hip/hip_runtime.h>
#include <math.h>

#define CLS_NUM 1000
#define FEAT 512
#define NPART 4            // count partial tables (one per count block)
#define CB_THREADS 1024
#define CB_WAVES (CB_THREADS / 64)

// ---------- helpers ----------

__device__ __forceinline__ bool detect_is64(const void* ys_raw) {
    // int64 (LE): high word of each element is 0, low word < 1000.
    // int32: odd words are random labels; all-zero across 16 slots ~ 1e-48.
    const int* y32 = (const int*)ys_raw;
    bool is64 = true;
#pragma unroll
    for (int k = 0; k < 16; ++k) {
        int lo = y32[2 * k], hi = y32[2 * k + 1];
        if (hi != 0 || (unsigned)lo >= (unsigned)CLS_NUM) is64 = false;
    }
    return is64;
}

__device__ __forceinline__ int load_label(const void* ys_raw, bool is64, int i) {
    return is64 ? (int)((const long long*)ys_raw)[i] : ((const int*)ys_raw)[i];
}

// ---------- node 1: label histogram into NPART partial tables ----------
// No global pre-zero needed: LDS sub-hists are zeroed in-kernel and the
// partial tables are fully STORED (not accumulated). Also zeroes out[0]
// (stream-ordered before dist_kernel's atomics).

__global__ __launch_bounds__(CB_THREADS) void count_hist(
    const void* __restrict__ ys_raw,
    unsigned* __restrict__ countP,   // [NPART][CLS_NUM]
    float* __restrict__ out,
    int n)
{
    __shared__ unsigned hist[CB_WAVES][CLS_NUM];
    const int t = (int)threadIdx.x;
    const bool is64 = detect_is64(ys_raw);

    for (int idx = t; idx < CB_WAVES * CLS_NUM; idx += CB_THREADS)
        ((unsigned*)hist)[idx] = 0u;
    __syncthreads();

    const int per_blk = (n + NPART - 1) / NPART;
    const int base = (int)blockIdx.x * per_blk;
    const int end  = min(base + per_blk, n);
    const int w = t >> 6;
    for (int i = base + t; i < end; i += CB_THREADS)
        atomicAdd(&hist[w][load_label(ys_raw, is64, i)], 1u);
    __syncthreads();

    for (int c = t; c < CLS_NUM; c += CB_THREADS) {
        unsigned s = 0;
#pragma unroll
        for (int k = 0; k < CB_WAVES; ++k) s += hist[k][c];
        countP[blockIdx.x * CLS_NUM + c] = s;
    }
    if (blockIdx.x == 0 && t == 0) out[0] = 0.f;
}

// ---------- node 2: streaming dist pass (R2-proven body) ----------
// One wave per sample: 512 floats = 64 lanes x 2 float4, fully coalesced.
// Count lookup: lanes 0..3 load one partial each, 2-step shuffle sum.

__global__ __launch_bounds__(256) void dist_kernel(
    const float* __restrict__ xs,
    const void* __restrict__ ys_raw,
    const float* __restrict__ center,
    const unsigned* __restrict__ countP,
    float* __restrict__ out,
    int n)
{
    const bool is64 = detect_is64(ys_raw);
    const int lane  = (int)threadIdx.x & 63;
    const int wave  = (int)((blockIdx.x * blockDim.x + threadIdx.x) >> 6);
    const int nwave = (int)((gridDim.x * blockDim.x) >> 6);

    __shared__ float bsum;
    if (threadIdx.x == 0) bsum = 0.f;
    __syncthreads();

    float wsum = 0.f;  // meaningful on lane 0 only

    for (int i = wave; i < n; i += nwave) {
        const int y = load_label(ys_raw, is64, i);
        const float4* xp = (const float4*)(xs + (size_t)i * FEAT);
        const float4* cp = (const float4*)(center + (size_t)y * FEAT);
        float4 x0 = xp[lane];
        float4 x1 = xp[lane + 64];
        float4 c0 = cp[lane];
        float4 c1 = cp[lane + 64];
        float d, s = 0.f;
        d = x0.x - c0.x; s += d * d;
        d = x0.y - c0.y; s += d * d;
        d = x0.z - c0.z; s += d * d;
        d = x0.w - c0.w; s += d * d;
        d = x1.x - c1.x; s += d * d;
        d = x1.y - c1.y; s += d * d;
        d = x1.z - c1.z; s += d * d;
        d = x1.w - c1.w; s += d * d;
#pragma unroll
        for (int off = 32; off; off >>= 1)
            s += __shfl_xor(s, off, 64);

        // per-class count: lanes 0..3 hold the 4 partials, sum over 4 lanes
        unsigned part = (lane < NPART) ? countP[lane * CLS_NUM + y] : 0u;
        part += __shfl_xor(part, 1, 64);
        part += __shfl_xor(part, 2, 64);

        if (lane == 0)
            wsum += sqrtf(s) / (float)part;
    }

    if (lane == 0) atomicAdd(&bsum, wsum);       // LDS atomic, one per wave
    __syncthreads();
    if (threadIdx.x == 0) atomicAdd(out, bsum);  // one global atomic per block
}

extern "C" void kernel_launch(void* const* d_in, const int* in_sizes, int n_in,
                              void* d_out, int out_size, void* d_ws, size_t ws_size,
                              hipStream_t stream)
{
    const float* xs     = (const float*)d_in[0];
    const void*  ys     = d_in[1];
    const float* center = (const float*)d_in[2];
    float* out = (float*)d_out;

    unsigned* countP = (unsigned*)d_ws;  // [NPART][CLS_NUM], fully stored each call

    const int n = in_sizes[1];  // number of samples (ys element count)

    count_hist<<<NPART, CB_THREADS, 0, stream>>>(ys, countP, out, n);
    dist_kernel<<<2048, 256, 0, stream>>>(xs, ys, center, countP, out, n);
}

// Round 8
// 56.972 us; speedup vs baseline: 4.6527x; 1.0487x over previous
//
#include <hip/hip_runtime.h>
#include <math.h>

#define CLS_NUM 1000
#define FEAT 512
#define NPART 16           // count partial tables (one per count block)
#define CB_THREADS 1024
#define CB_WAVES (CB_THREADS / 64)

// ---------- helpers ----------

__device__ __forceinline__ bool detect_is64(const void* ys_raw) {
    // int64 (LE): high word of each element is 0, low word < 1000.
    // int32: odd words are random labels; all-zero across 16 slots ~ 1e-48.
    const int* y32 = (const int*)ys_raw;
    bool is64 = true;
#pragma unroll
    for (int k = 0; k < 16; ++k) {
        int lo = y32[2 * k], hi = y32[2 * k + 1];
        if (hi != 0 || (unsigned)lo >= (unsigned)CLS_NUM) is64 = false;
    }
    return is64;
}

__device__ __forceinline__ int load_label(const void* ys_raw, bool is64, int i) {
    return is64 ? (int)((const long long*)ys_raw)[i] : ((const int*)ys_raw)[i];
}

// ---------- node 1: label histogram into NPART partial tables ----------
// 16 blocks x 1024 threads: 16 CUs stream the 512 KB label array (4096
// labels/block, 4/thread). Per-wave LDS sub-hists (64 KB) -> store-only
// TRANSPOSED partials countP[c*NPART + b] so dist's lookup is one
// contiguous 64 B line. No global pre-zero anywhere. Also zeroes out[0].

__global__ __launch_bounds__(CB_THREADS) void count_hist(
    const void* __restrict__ ys_raw,
    unsigned* __restrict__ countP,   // [CLS_NUM][NPART] transposed
    float* __restrict__ out,
    int n)
{
    __shared__ unsigned hist[CB_WAVES][CLS_NUM];
    const int t = (int)threadIdx.x;
    const bool is64 = detect_is64(ys_raw);

    for (int idx = t; idx < CB_WAVES * CLS_NUM; idx += CB_THREADS)
        ((unsigned*)hist)[idx] = 0u;
    __syncthreads();

    const int per_blk = (n + NPART - 1) / NPART;
    const int base = (int)blockIdx.x * per_blk;
    const int end  = min(base + per_blk, n);
    const int w = t >> 6;
    for (int i = base + t; i < end; i += CB_THREADS)
        atomicAdd(&hist[w][load_label(ys_raw, is64, i)], 1u);
    __syncthreads();

    for (int c = t; c < CLS_NUM; c += CB_THREADS) {
        unsigned s = 0;
#pragma unroll
        for (int k = 0; k < CB_WAVES; ++k) s += hist[k][c];
        countP[c * NPART + blockIdx.x] = s;   // transposed store
    }
    if (blockIdx.x == 0 && t == 0) out[0] = 0.f;
}

// ---------- node 2: streaming dist pass (R2-proven body) ----------
// One wave per sample: 512 floats = 64 lanes x 2 float4, fully coalesced.
// Count lookup: lanes 0..15 load countP[y*16+lane] (one 64 B line),
// 4-step xor-shuffle sum (offsets <16 keep lanes 0..15 closed).

__global__ __launch_bounds__(256) void dist_kernel(
    const float* __restrict__ xs,
    const void* __restrict__ ys_raw,
    const float* __restrict__ center,
    const unsigned* __restrict__ countP,
    float* __restrict__ out,
    int n)
{
    const bool is64 = detect_is64(ys_raw);
    const int lane  = (int)threadIdx.x & 63;
    const int wave  = (int)((blockIdx.x * blockDim.x + threadIdx.x) >> 6);
    const int nwave = (int)((gridDim.x * blockDim.x) >> 6);

    __shared__ float bsum;
    if (threadIdx.x == 0) bsum = 0.f;
    __syncthreads();

    float wsum = 0.f;  // meaningful on lane 0 only

    for (int i = wave; i < n; i += nwave) {
        const int y = load_label(ys_raw, is64, i);
        const float4* xp = (const float4*)(xs + (size_t)i * FEAT);
        const float4* cp = (const float4*)(center + (size_t)y * FEAT);
        float4 x0 = xp[lane];
        float4 x1 = xp[lane + 64];
        float4 c0 = cp[lane];
        float4 c1 = cp[lane + 64];
        float d, s = 0.f;
        d = x0.x - c0.x; s += d * d;
        d = x0.y - c0.y; s += d * d;
        d = x0.z - c0.z; s += d * d;
        d = x0.w - c0.w; s += d * d;
        d = x1.x - c1.x; s += d * d;
        d = x1.y - c1.y; s += d * d;
        d = x1.z - c1.z; s += d * d;
        d = x1.w - c1.w; s += d * d;
#pragma unroll
        for (int off = 32; off; off >>= 1)
            s += __shfl_xor(s, off, 64);

        // per-class count: lanes 0..15 hold the 16 partials (coalesced line)
        unsigned part = (lane < NPART) ? countP[y * NPART + lane] : 0u;
        part += __shfl_xor(part, 1, 64);
        part += __shfl_xor(part, 2, 64);
        part += __shfl_xor(part, 4, 64);
        part += __shfl_xor(part, 8, 64);

        if (lane == 0)
            wsum += sqrtf(s) / (float)part;
    }

    if (lane == 0) atomicAdd(&bsum, wsum);       // LDS atomic, one per wave
    __syncthreads();
    if (threadIdx.x == 0) atomicAdd(out, bsum);  // one global atomic per block
}

extern "C" void kernel_launch(void* const* d_in, const int* in_sizes, int n_in,
                              void* d_out, int out_size, void* d_ws, size_t ws_size,
                              hipStream_t stream)
{
    const float* xs     = (const float*)d_in[0];
    const void*  ys     = d_in[1];
    const float* center = (const float*)d_in[2];
    float* out = (float*)d_out;

    unsigned* countP = (unsigned*)d_ws;  // [CLS_NUM][NPART], fully stored each call

    const int n = in_sizes[1];  // number of samples (ys element count)

    count_hist<<<NPART, CB_THREADS, 0, stream>>>(ys, countP, out, n);
    dist_kernel<<<2048, 256, 0, stream>>>(xs, ys, center, countP, out, n);
}